// Round 2
// baseline (5828.049 us; speedup 1.0000x reference)
//
#include <hip/hip_runtime.h>
#include <stdint.h>

typedef __attribute__((ext_vector_type(8))) short short8;
typedef __attribute__((ext_vector_type(4))) float f32x4;

#define T_SZ 512

// ws layout (bytes)
#define XP_OFF    0ull                 // xp (bf16): 16384*4096*2 = 134217728
#define UPERM_OFF 134217728ull         // Uperm (bf16): 8 MB
#define WPERM_OFF 142606336ull         // Wperm (bf16): 4 MB
#define HBUF_OFF  146800640ull         // hbuf: 2*32*1024*2 = 131072
#define BAR_OFF   146931712ull         // barrier: 1024 B

static __device__ __forceinline__ float b2f(unsigned short u) {
  unsigned v = ((unsigned)u) << 16;
  return __builtin_bit_cast(float, v);
}
static __device__ __forceinline__ unsigned short f2b(float f) {
  unsigned u = __builtin_bit_cast(unsigned, f);
  u += 0x7fffu + ((u >> 16) & 1u);   // RNE
  return (unsigned short)(u >> 16);
}
static __device__ __forceinline__ float sigm(float x) {
  return 1.0f / (1.0f + __expf(-x));
}
static __device__ __forceinline__ float tanh_f(float x) {
  return 1.0f - 2.0f / (__expf(2.0f * x) + 1.0f);
}

// ---- one-time permutation of U (f32 -> bf16) into MFMA B-fragment layout ----
// frag F = ((cg*4 + kq)*4 + g)*8 + kk ; lane l holds B[k][n],
// k = kq*256+kk*32+(l>>4)*8+j, n = g*1024+cg*16+(l&15)
__global__ void permute_U(const float* __restrict__ U, unsigned short* __restrict__ Up) {
  int t = blockIdx.x * 256 + threadIdx.x;        // 524288 threads
  int l = t & 63;
  int F = t >> 6;                                 // 8192 frags
  int kk = F & 7, g = (F >> 3) & 3, kq = (F >> 5) & 3, cg = F >> 7;
  int k0 = kq * 256 + kk * 32 + (l >> 4) * 8;
  int n  = g * 1024 + cg * 16 + (l & 15);
  unsigned short v[8];
#pragma unroll
  for (int j = 0; j < 8; j++) v[j] = f2b(U[(size_t)(k0 + j) * 4096 + n]);
  unsigned short* dst = Up + (size_t)t * 8;
#pragma unroll
  for (int j = 0; j < 8; j++) dst[j] = v[j];
}

// frag F = nt*16 + kk ; k = kk*32+(l>>4)*8+j (k<512), n = nt*16+(l&15)
__global__ void permute_W(const float* __restrict__ W, unsigned short* __restrict__ Wp) {
  int t = blockIdx.x * 256 + threadIdx.x;        // 262144 threads
  int l = t & 63;
  int F = t >> 6;                                 // 4096 frags
  int kk = F & 15, nt = F >> 4;
  int k0 = kk * 32 + (l >> 4) * 8;
  int n  = nt * 16 + (l & 15);
  unsigned short v[8];
#pragma unroll
  for (int j = 0; j < 8; j++) v[j] = f2b(W[(size_t)(k0 + j) * 4096 + n]);
  unsigned short* dst = Wp + (size_t)t * 8;
#pragma unroll
  for (int j = 0; j < 8; j++) dst[j] = v[j];
}

__global__ void init_zero(unsigned short* __restrict__ hbuf, unsigned* __restrict__ bar) {
  int t = blockIdx.x * 256 + threadIdx.x;
  if (t < 16384) ((unsigned long long*)hbuf)[t] = 0ull;   // 2*32*1024 bf16
  if (t < 256) bar[t] = 0u;
}

// ---- Phase B: xp[m][n] = X[m][:] @ W[:][n] + b[n], M=16384 N=4096 K=512 ----
// X is f32 (converted to bf16 during LDS staging); xp stored bf16.
__global__ __launch_bounds__(256) void xproj_gemm(
    const float* __restrict__ X,
    const unsigned short* __restrict__ Wp,
    const float* __restrict__ bias,
    unsigned short* __restrict__ xp) {
  const int tid = threadIdx.x;
  const int l = tid & 63;
  const int w = tid >> 6;
  const int wr = w >> 1, wc = w & 1;
  const int bn = blockIdx.x;   // 32
  const int bm = blockIdx.y;   // 128
  const int quad = l >> 4, lane16 = l & 15;
  __shared__ unsigned short lA[128 * 72];   // 128 rows x 64 k (bf16), +8 pad

  f32x4 acc[4][4];
#pragma unroll
  for (int i = 0; i < 4; i++)
#pragma unroll
    for (int j = 0; j < 4; j++) acc[i][j] = (f32x4){0.f, 0.f, 0.f, 0.f};

  const int m0 = bm * 128;
  const int sr = tid >> 3;          // 0..31
  const int sc = (tid & 7) * 8;     // 0..56 (floats)

  for (int ks = 0; ks < 8; ks++) {
    __syncthreads();
#pragma unroll
    for (int it = 0; it < 4; it++) {
      int row = sr + it * 32;
      const float* src = X + (size_t)(m0 + row) * 512 + ks * 64 + sc;
      float4 a = *(const float4*)(src);
      float4 c = *(const float4*)(src + 4);
      unsigned short tmp[8] = {f2b(a.x), f2b(a.y), f2b(a.z), f2b(a.w),
                               f2b(c.x), f2b(c.y), f2b(c.z), f2b(c.w)};
      *(int4*)(lA + row * 72 + sc) = *(const int4*)tmp;
    }
    __syncthreads();
#pragma unroll
    for (int kk = 0; kk < 2; kk++) {
      short8 af[4], bf[4];
#pragma unroll
      for (int i = 0; i < 4; i++)
        af[i] = *(const short8*)(lA + (wr * 64 + i * 16 + lane16) * 72 + kk * 32 + quad * 8);
#pragma unroll
      for (int j = 0; j < 4; j++) {
        int F = (bn * 8 + wc * 4 + j) * 16 + ks * 2 + kk;
        bf[j] = *(const short8*)(Wp + (size_t)(F * 64 + l) * 8);
      }
#pragma unroll
      for (int i = 0; i < 4; i++)
#pragma unroll
        for (int j = 0; j < 4; j++)
          acc[i][j] = __builtin_amdgcn_mfma_f32_16x16x32_bf16(af[i], bf[j], acc[i][j], 0, 0, 0);
    }
  }
#pragma unroll
  for (int j = 0; j < 4; j++) {
    int n = bn * 128 + wc * 64 + j * 16 + lane16;
    float bj = bias[n];
#pragma unroll
    for (int i = 0; i < 4; i++)
#pragma unroll
      for (int r = 0; r < 4; r++) {
        int m = m0 + wr * 64 + i * 16 + quad * 4 + r;
        xp[(size_t)m * 4096 + n] = f2b(acc[i][j][r] + bj);
      }
  }
}

// ---- Phase C: persistent recurrent kernel ----
// 128 blocks x 256 threads. block: mh = batch-half (16 rows), cg = 16 h-cols.
// wave kq holds U-frags for its K-quarter in registers (128 VGPRs), all 512 steps.
__global__ __launch_bounds__(256, 1) void lstm_rec(
    const unsigned short* __restrict__ xp,
    const unsigned short* __restrict__ Up,
    unsigned short* __restrict__ hbuf,   // [2][32][1024] bf16
    unsigned* __restrict__ bar,
    float* __restrict__ out) {           // [32][512][1024] f32
  const int tid = threadIdx.x;
  const int l = tid & 63;
  const int kq = tid >> 6;           // wave = K-quarter
  const int bid = blockIdx.x;        // 0..127
  const int mh = bid >> 6;           // team (batch half)
  const int cg = bid & 63;           // h-col group
  const int quad = l >> 4, lane16 = l & 15;

  __shared__ unsigned short lh[16 * 1032];     // 16 batches x 1024 k (+8 pad)
  __shared__ float zbuf[4][4][16][17];         // [kq][gate][b][col]

  // preload B fragments (U slice) into registers: 4 gates x 8 k-frags x 16B
  short8 bfr[4][8];
#pragma unroll
  for (int g = 0; g < 4; g++)
#pragma unroll
    for (int kk = 0; kk < 8; kk++) {
      int F = ((cg * 4 + kq) * 4 + g) * 8 + kk;
      bfr[g][kk] = *(const short8*)(Up + (size_t)(F * 64 + l) * 8);
    }

  float c_st = 0.0f;
  const int bl = tid >> 4;           // 0..15
  const int jj = tid & 15;
  const int bglob = mh * 16 + bl;

  unsigned* cnt = bar + mh * 128;        // teams 512B apart
  unsigned* gen = bar + mh * 128 + 32;   // separate 128B line

#pragma unroll 1
  for (int t = 0; t < T_SZ; t++) {
    // stage h(t) for this batch-half into LDS (32 KB)
    const unsigned short* hr = hbuf + ((size_t)(t & 1) * 32 + mh * 16) * 1024;
#pragma unroll
    for (int i = 0; i < 8; i++) {
      int u = tid + i * 256;           // 0..2047 x 16B
      int row = u >> 7, cu = u & 127;
      *(int4*)(lh + row * 1032 + cu * 8) = *(const int4*)(hr + row * 1024 + cu * 8);
    }
    __syncthreads();

    // z partial GEMM: wave kq covers k in [kq*256, kq*256+256)
    f32x4 acc[4];
#pragma unroll
    for (int g = 0; g < 4; g++) acc[g] = (f32x4){0.f, 0.f, 0.f, 0.f};
#pragma unroll
    for (int kk = 0; kk < 8; kk++) {
      short8 af = *(const short8*)(lh + lane16 * 1032 + kq * 256 + kk * 32 + quad * 8);
#pragma unroll
      for (int g = 0; g < 4; g++)
        acc[g] = __builtin_amdgcn_mfma_f32_16x16x32_bf16(af, bfr[g][kk], acc[g], 0, 0, 0);
    }
#pragma unroll
    for (int g = 0; g < 4; g++)
#pragma unroll
      for (int r = 0; r < 4; r++)
        zbuf[kq][g][quad * 4 + r][lane16] = acc[g][r];
    __syncthreads();

    // elementwise: thread -> (batch bl, h-col jj)
    const size_t xpb = ((size_t)bglob * T_SZ + t) * 4096 + (size_t)cg * 16 + jj;
    float z[4];
#pragma unroll
    for (int g = 0; g < 4; g++)
      z[g] = zbuf[0][g][bl][jj] + zbuf[1][g][bl][jj] + zbuf[2][g][bl][jj] + zbuf[3][g][bl][jj]
           + b2f(xp[xpb + (size_t)g * 1024]);
    float ig = sigm(z[0]);
    float fg = sigm(z[1]);
    float gg = tanh_f(z[2]);
    float og = sigm(z[3]);
    c_st = fg * c_st + ig * gg;
    float h = og * tanh_f(c_st);
    out[((size_t)bglob * T_SZ + t) * 1024 + cg * 16 + jj] = h;
    hbuf[((size_t)((t + 1) & 1) * 32 + bglob) * 1024 + cg * 16 + jj] = f2b(h);

    // team barrier (64 blocks; batch halves are independent)
    __syncthreads();   // drains vmcnt for all waves -> stores are in L2
    if (tid == 0) {
      __threadfence();                               // release
      unsigned g0 = __hip_atomic_load(gen, __ATOMIC_RELAXED, __HIP_MEMORY_SCOPE_AGENT);
      unsigned old = __hip_atomic_fetch_add(cnt, 1u, __ATOMIC_ACQ_REL, __HIP_MEMORY_SCOPE_AGENT);
      if (old == 63u) {
        __hip_atomic_store(cnt, 0u, __ATOMIC_RELAXED, __HIP_MEMORY_SCOPE_AGENT);
        __hip_atomic_store(gen, g0 + 1u, __ATOMIC_RELEASE, __HIP_MEMORY_SCOPE_AGENT);
      } else {
        while (__hip_atomic_load(gen, __ATOMIC_RELAXED, __HIP_MEMORY_SCOPE_AGENT) == g0)
          __builtin_amdgcn_s_sleep(1);
      }
      __threadfence();                               // acquire
    }
    __syncthreads();
  }
}

extern "C" void kernel_launch(void* const* d_in, const int* in_sizes, int n_in,
                              void* d_out, int out_size, void* d_ws, size_t ws_size,
                              hipStream_t stream) {
  const float* X    = (const float*)d_in[0];  // [32][512][512]  f32
  const float* W    = (const float*)d_in[1];  // [512][4096]     f32
  const float* U    = (const float*)d_in[2];  // [1024][4096]    f32
  const float* bias = (const float*)d_in[3];  // [4096]          f32
  float* out = (float*)d_out;                 // [32][512][1024] f32

  char* ws = (char*)d_ws;
  unsigned short* xp   = (unsigned short*)(ws + XP_OFF);
  unsigned short* Up   = (unsigned short*)(ws + UPERM_OFF);
  unsigned short* Wp   = (unsigned short*)(ws + WPERM_OFF);
  unsigned short* hbuf = (unsigned short*)(ws + HBUF_OFF);
  unsigned*       bar  = (unsigned*)(ws + BAR_OFF);

  hipLaunchKernelGGL(permute_U, dim3(2048), dim3(256), 0, stream, U, Up);
  hipLaunchKernelGGL(permute_W, dim3(1024), dim3(256), 0, stream, W, Wp);
  hipLaunchKernelGGL(init_zero, dim3(64), dim3(256), 0, stream, hbuf, bar);
  hipLaunchKernelGGL(xproj_gemm, dim3(32, 128), dim3(256), 0, stream, X, Wp, bias, xp);
  hipLaunchKernelGGL(lstm_rec, dim3(128), dim3(256), 0, stream, xp, Up, hbuf, bar, out);
}

// Round 3
// 4321.431 us; speedup vs baseline: 1.3486x; 1.3486x over previous
//
#include <hip/hip_runtime.h>
#include <stdint.h>

typedef __attribute__((ext_vector_type(8))) short short8;
typedef __attribute__((ext_vector_type(4))) float f32x4;

#define T_SZ 512

// ws layout (bytes)
#define XP_OFF    0ull                 // xp (bf16): 16384*4096*2 = 134217728
#define UPERM_OFF 134217728ull         // Uperm (bf16): 8 MB
#define WPERM_OFF 142606336ull         // Wperm (bf16): 4 MB
#define HBUF_OFF  146800640ull         // hbuf: 2*32*1024*2 = 131072
#define BAR_OFF   146931712ull         // flags: team0 [0..63], team1 [64..127]

static __device__ __forceinline__ float b2f(unsigned short u) {
  unsigned v = ((unsigned)u) << 16;
  return __builtin_bit_cast(float, v);
}
static __device__ __forceinline__ unsigned short f2b(float f) {
  unsigned u = __builtin_bit_cast(unsigned, f);
  u += 0x7fffu + ((u >> 16) & 1u);   // RNE
  return (unsigned short)(u >> 16);
}
static __device__ __forceinline__ float sigm(float x) {
  return 1.0f / (1.0f + __expf(-x));
}
static __device__ __forceinline__ float tanh_f(float x) {
  return 1.0f - 2.0f / (__expf(2.0f * x) + 1.0f);
}

// ---- one-time permutation of U (f32 -> bf16) into MFMA B-fragment layout ----
// frag F = ((cg*4 + kq)*4 + g)*8 + kk ; lane l holds B[k][n],
// k = kq*256+kk*32+(l>>4)*8+j, n = g*1024+cg*16+(l&15)
__global__ void permute_U(const float* __restrict__ U, unsigned short* __restrict__ Up) {
  int t = blockIdx.x * 256 + threadIdx.x;        // 524288 threads
  int l = t & 63;
  int F = t >> 6;                                 // 8192 frags
  int kk = F & 7, g = (F >> 3) & 3, kq = (F >> 5) & 3, cg = F >> 7;
  int k0 = kq * 256 + kk * 32 + (l >> 4) * 8;
  int n  = g * 1024 + cg * 16 + (l & 15);
  unsigned short v[8];
#pragma unroll
  for (int j = 0; j < 8; j++) v[j] = f2b(U[(size_t)(k0 + j) * 4096 + n]);
  unsigned short* dst = Up + (size_t)t * 8;
#pragma unroll
  for (int j = 0; j < 8; j++) dst[j] = v[j];
}

// frag F = nt*16 + kk ; k = kk*32+(l>>4)*8+j (k<512), n = nt*16+(l&15)
__global__ void permute_W(const float* __restrict__ W, unsigned short* __restrict__ Wp) {
  int t = blockIdx.x * 256 + threadIdx.x;        // 262144 threads
  int l = t & 63;
  int F = t >> 6;                                 // 4096 frags
  int kk = F & 15, nt = F >> 4;
  int k0 = kk * 32 + (l >> 4) * 8;
  int n  = nt * 16 + (l & 15);
  unsigned short v[8];
#pragma unroll
  for (int j = 0; j < 8; j++) v[j] = f2b(W[(size_t)(k0 + j) * 4096 + n]);
  unsigned short* dst = Wp + (size_t)t * 8;
#pragma unroll
  for (int j = 0; j < 8; j++) dst[j] = v[j];
}

__global__ void init_zero(unsigned short* __restrict__ hbuf, unsigned* __restrict__ bar) {
  int t = blockIdx.x * 256 + threadIdx.x;
  if (t < 16384) ((unsigned long long*)hbuf)[t] = 0ull;   // 2*32*1024 bf16
  if (t < 256) bar[t] = 0u;
}

// ---- Phase B: xp[m][n] = X[m][:] @ W[:][n] + b[n], M=16384 N=4096 K=512 ----
__global__ __launch_bounds__(256) void xproj_gemm(
    const float* __restrict__ X,
    const unsigned short* __restrict__ Wp,
    const float* __restrict__ bias,
    unsigned short* __restrict__ xp) {
  const int tid = threadIdx.x;
  const int l = tid & 63;
  const int w = tid >> 6;
  const int wr = w >> 1, wc = w & 1;
  const int bn = blockIdx.x;   // 32
  const int bm = blockIdx.y;   // 128
  const int quad = l >> 4, lane16 = l & 15;
  __shared__ unsigned short lA[128 * 72];   // 128 rows x 64 k (bf16), +8 pad

  f32x4 acc[4][4];
#pragma unroll
  for (int i = 0; i < 4; i++)
#pragma unroll
    for (int j = 0; j < 4; j++) acc[i][j] = (f32x4){0.f, 0.f, 0.f, 0.f};

  const int m0 = bm * 128;
  const int sr = tid >> 3;          // 0..31
  const int sc = (tid & 7) * 8;     // 0..56 (floats)

  for (int ks = 0; ks < 8; ks++) {
    __syncthreads();
#pragma unroll
    for (int it = 0; it < 4; it++) {
      int row = sr + it * 32;
      const float* src = X + (size_t)(m0 + row) * 512 + ks * 64 + sc;
      float4 a = *(const float4*)(src);
      float4 c = *(const float4*)(src + 4);
      unsigned short tmp[8] = {f2b(a.x), f2b(a.y), f2b(a.z), f2b(a.w),
                               f2b(c.x), f2b(c.y), f2b(c.z), f2b(c.w)};
      *(int4*)(lA + row * 72 + sc) = *(const int4*)tmp;
    }
    __syncthreads();
#pragma unroll
    for (int kk = 0; kk < 2; kk++) {
      short8 af[4], bf[4];
#pragma unroll
      for (int i = 0; i < 4; i++)
        af[i] = *(const short8*)(lA + (wr * 64 + i * 16 + lane16) * 72 + kk * 32 + quad * 8);
#pragma unroll
      for (int j = 0; j < 4; j++) {
        int F = (bn * 8 + wc * 4 + j) * 16 + ks * 2 + kk;
        bf[j] = *(const short8*)(Wp + (size_t)(F * 64 + l) * 8);
      }
#pragma unroll
      for (int i = 0; i < 4; i++)
#pragma unroll
        for (int j = 0; j < 4; j++)
          acc[i][j] = __builtin_amdgcn_mfma_f32_16x16x32_bf16(af[i], bf[j], acc[i][j], 0, 0, 0);
    }
  }
#pragma unroll
  for (int j = 0; j < 4; j++) {
    int n = bn * 128 + wc * 64 + j * 16 + lane16;
    float bj = bias[n];
#pragma unroll
    for (int i = 0; i < 4; i++)
#pragma unroll
      for (int r = 0; r < 4; r++) {
        int m = m0 + wr * 64 + i * 16 + quad * 4 + r;
        xp[(size_t)m * 4096 + n] = f2b(acc[i][j][r] + bj);
      }
  }
}

// ---- Phase C: persistent recurrent kernel ----
// 128 blocks x 256 threads. block: mh = batch-half (16 rows), cg = 16 h-cols.
// Barrier = flag array: 64 parallel release-stores + 64-lane ballot poll
// (replaces serialized fetch_add convoy: 64 x ~150ns RMW was ~9.6us/step).
__global__ __launch_bounds__(256, 1) void lstm_rec(
    const unsigned short* __restrict__ xp,
    const unsigned short* __restrict__ Up,
    unsigned short* __restrict__ hbuf,   // [2][32][1024] bf16
    unsigned* __restrict__ bar,
    float* __restrict__ out) {           // [32][512][1024] f32
  const int tid = threadIdx.x;
  const int l = tid & 63;
  const int kq = tid >> 6;           // wave = K-quarter
  const int bid = blockIdx.x;        // 0..127
  const int mh = bid >> 6;           // team (batch half)
  const int cg = bid & 63;           // h-col group
  const int quad = l >> 4, lane16 = l & 15;

  __shared__ unsigned short lh[16 * 1032];     // 16 batches x 1024 k (+8 pad)
  __shared__ float zbuf[4][4][16][17];         // [kq][gate][b][col]

  // preload B fragments (U slice) into registers: 4 gates x 8 k-frags x 16B
  short8 bfr[4][8];
#pragma unroll
  for (int g = 0; g < 4; g++)
#pragma unroll
    for (int kk = 0; kk < 8; kk++) {
      int F = ((cg * 4 + kq) * 4 + g) * 8 + kk;
      bfr[g][kk] = *(const short8*)(Up + (size_t)(F * 64 + l) * 8);
    }

  float c_st = 0.0f;
  const int bl = tid >> 4;           // 0..15
  const int jj = tid & 15;
  const int bglob = mh * 16 + bl;

  unsigned* flags = bar + mh * 64;   // 64 flags per team, teams 256B apart

#pragma unroll 1
  for (int t = 0; t < T_SZ; t++) {
    // prefetch xp(t): off the producer critical path, hides under h staging
    const unsigned short* xpp =
        xp + ((size_t)bglob * T_SZ + t) * 4096 + (size_t)cg * 16 + jj;
    unsigned short xr0 = xpp[0];
    unsigned short xr1 = xpp[1024];
    unsigned short xr2 = xpp[2048];
    unsigned short xr3 = xpp[3072];

    // stage h(t) for this batch-half into LDS (32 KB)
    const unsigned short* hr = hbuf + ((size_t)(t & 1) * 32 + mh * 16) * 1024;
#pragma unroll
    for (int i = 0; i < 8; i++) {
      int u = tid + i * 256;           // 0..2047 x 16B
      int row = u >> 7, cu = u & 127;
      *(int4*)(lh + row * 1032 + cu * 8) = *(const int4*)(hr + row * 1024 + cu * 8);
    }
    __syncthreads();

    // z partial GEMM: wave kq covers k in [kq*256, kq*256+256)
    f32x4 acc[4];
#pragma unroll
    for (int g = 0; g < 4; g++) acc[g] = (f32x4){0.f, 0.f, 0.f, 0.f};
#pragma unroll
    for (int kk = 0; kk < 8; kk++) {
      short8 af = *(const short8*)(lh + lane16 * 1032 + kq * 256 + kk * 32 + quad * 8);
#pragma unroll
      for (int g = 0; g < 4; g++)
        acc[g] = __builtin_amdgcn_mfma_f32_16x16x32_bf16(af, bfr[g][kk], acc[g], 0, 0, 0);
    }
#pragma unroll
    for (int g = 0; g < 4; g++)
#pragma unroll
      for (int r = 0; r < 4; r++)
        zbuf[kq][g][quad * 4 + r][lane16] = acc[g][r];
    __syncthreads();

    // elementwise: thread -> (batch bl, h-col jj)
    float z0 = zbuf[0][0][bl][jj] + zbuf[1][0][bl][jj] + zbuf[2][0][bl][jj] + zbuf[3][0][bl][jj] + b2f(xr0);
    float z1 = zbuf[0][1][bl][jj] + zbuf[1][1][bl][jj] + zbuf[2][1][bl][jj] + zbuf[3][1][bl][jj] + b2f(xr1);
    float z2 = zbuf[0][2][bl][jj] + zbuf[1][2][bl][jj] + zbuf[2][2][bl][jj] + zbuf[3][2][bl][jj] + b2f(xr2);
    float z3 = zbuf[0][3][bl][jj] + zbuf[1][3][bl][jj] + zbuf[2][3][bl][jj] + zbuf[3][3][bl][jj] + b2f(xr3);
    float ig = sigm(z0);
    float fg = sigm(z1);
    float gg = tanh_f(z2);
    float og = sigm(z3);
    c_st = fg * c_st + ig * gg;
    float h = og * tanh_f(c_st);
    out[((size_t)bglob * T_SZ + t) * 1024 + cg * 16 + jj] = h;
    hbuf[((size_t)((t + 1) & 1) * 32 + bglob) * 1024 + cg * 16 + jj] = f2b(h);

    // team barrier: flag-array (64 independent stores + parallel ballot poll)
    __syncthreads();   // all waves drain vmcnt -> h stores are in L2
    if (tid == 0) {
      // release store: flush L2, publish "finished step t"
      __hip_atomic_store(&flags[cg], (unsigned)(t + 1),
                         __ATOMIC_RELEASE, __HIP_MEMORY_SCOPE_AGENT);
    }
    if (tid < 64) {
      const unsigned target = (unsigned)(t + 1);
      while (true) {
        unsigned v = __hip_atomic_load(&flags[tid], __ATOMIC_RELAXED,
                                       __HIP_MEMORY_SCOPE_AGENT);
        if (__ballot(v < target) == 0ull) break;
        __builtin_amdgcn_s_sleep(1);
      }
      __builtin_amdgcn_fence(__ATOMIC_ACQUIRE, "agent");  // invalidate stale h lines
    }
    __syncthreads();
  }
}

extern "C" void kernel_launch(void* const* d_in, const int* in_sizes, int n_in,
                              void* d_out, int out_size, void* d_ws, size_t ws_size,
                              hipStream_t stream) {
  const float* X    = (const float*)d_in[0];  // [32][512][512]  f32
  const float* W    = (const float*)d_in[1];  // [512][4096]     f32
  const float* U    = (const float*)d_in[2];  // [1024][4096]    f32
  const float* bias = (const float*)d_in[3];  // [4096]          f32
  float* out = (float*)d_out;                 // [32][512][1024] f32

  char* ws = (char*)d_ws;
  unsigned short* xp   = (unsigned short*)(ws + XP_OFF);
  unsigned short* Up   = (unsigned short*)(ws + UPERM_OFF);
  unsigned short* Wp   = (unsigned short*)(ws + WPERM_OFF);
  unsigned short* hbuf = (unsigned short*)(ws + HBUF_OFF);
  unsigned*       bar  = (unsigned*)(ws + BAR_OFF);

  hipLaunchKernelGGL(permute_U, dim3(2048), dim3(256), 0, stream, U, Up);
  hipLaunchKernelGGL(permute_W, dim3(1024), dim3(256), 0, stream, W, Wp);
  hipLaunchKernelGGL(init_zero, dim3(64), dim3(256), 0, stream, hbuf, bar);
  hipLaunchKernelGGL(xproj_gemm, dim3(32, 128), dim3(256), 0, stream, X, Wp, bias, xp);
  hipLaunchKernelGGL(lstm_rec, dim3(128), dim3(256), 0, stream, xp, Up, hbuf, bar, out);
}